// Round 4
// baseline (196.426 us; speedup 1.0000x reference)
//
#include <hip/hip_runtime.h>

// SplatAwareFeedForward on MI355X (gfx950).
// Pipeline: cast/transpose to bf16 -> route tokens by expert -> expert GEMMs (m97-style)
//           -> dense aggregator GEMMs (256x256x64, m201-style 8-phase counted-vmcnt schedule).
// Workspace layout (bytes), total ~96.5 MB:
//   xb    @ 0        : 33,554,432  (B*S*D bf16; reused as g-buffer for GEMM4 input)
//   w1t   @ 33554432 :  8,388,608  (E*[H][D] bf16, transposed W1)
//   w2t   @ 41943040 :  8,388,608  (E*[D][H] bf16, transposed W2)
//   wg1t  @ 50331648 :  2,097,152  ([D][D] bf16, transposed Wg1)
//   wg2t  @ 52428800 :  2,097,152  ([D][D] bf16, transposed Wg2)
//   hbuf  @ 54525952 :  8,388,608  (B*S*H bf16, expert-sorted hidden)
//   rout  @ 62914560 : 33,554,432  (B*S*D bf16, routed output, natural order)
//   offs  @ 96468992 : 68          (E+1 ints)
//   order @ 96469248 : 16,384      (S ints, token s-indices sorted by expert)

#define DEV __device__ __forceinline__

typedef float f32x4 __attribute__((ext_vector_type(4)));
typedef short short8 __attribute__((ext_vector_type(8)));

DEV unsigned short f2bf(float f) {
  unsigned u = __float_as_uint(f);
  u += 0x7fffu + ((u >> 16) & 1u);   // round-to-nearest-even
  return (unsigned short)(u >> 16);
}

DEV void gload_lds16(const void* g, void* l) {
  __builtin_amdgcn_global_load_lds(
      (const __attribute__((address_space(1))) unsigned int*)g,
      (__attribute__((address_space(3))) unsigned int*)l, 16, 0, 0);
}

DEV float gelu_exact(float v) {
  return 0.5f * v * (1.0f + erff(v * 0.70710678118654752f));
}

#define BARRIER() __builtin_amdgcn_s_barrier()
#define VMW(n)    asm volatile("s_waitcnt vmcnt(" #n ")" ::: "memory")

// ---------------- cast fp32 -> bf16 (vectorized) ----------------
__global__ __launch_bounds__(256) void cast_bf16_kernel(
    const float* __restrict__ in, unsigned short* __restrict__ out, long n) {
  long i = ((long)blockIdx.x * 256 + threadIdx.x) * 8;
  if (i >= n) return;
  float4 v0 = *(const float4*)(in + i);
  float4 v1 = *(const float4*)(in + i + 4);
  uint4 o;
  o.x = (unsigned)f2bf(v0.x) | ((unsigned)f2bf(v0.y) << 16);
  o.y = (unsigned)f2bf(v0.z) | ((unsigned)f2bf(v0.w) << 16);
  o.z = (unsigned)f2bf(v1.x) | ((unsigned)f2bf(v1.y) << 16);
  o.w = (unsigned)f2bf(v1.z) | ((unsigned)f2bf(v1.w) << 16);
  *(uint4*)(out + i) = o;
}

// ---------------- transpose-cast: in [R][C] f32 -> out [C][R] bf16, E matrices ----------------
__global__ __launch_bounds__(256) void tcast_kernel(
    const float* __restrict__ in, unsigned short* __restrict__ out,
    int R, int C, long stride) {
  __shared__ float tile[64][65];
  const int t = threadIdx.x;
  const long base = (long)blockIdx.z * stride;
  const int r0 = blockIdx.y * 64, c0 = blockIdx.x * 64;
  const int cc = t & 63, rr = t >> 6;
#pragma unroll
  for (int i = 0; i < 16; i++) {
    int r = rr + i * 4;
    tile[r][cc] = in[base + (long)(r0 + r) * C + (c0 + cc)];
  }
  __syncthreads();
#pragma unroll
  for (int i = 0; i < 16; i++) {
    int c = rr + i * 4;
    out[base + (long)(c0 + c) * R + (r0 + cc)] = f2bf(tile[cc][c]);
  }
}

// ---------------- routing: counts -> prefix -> sorted order ----------------
__global__ __launch_bounds__(256) void route_kernel(
    const int* __restrict__ sid, int S, int* __restrict__ offs, int* __restrict__ order) {
  __shared__ int cnt[16], cur[16];
  const int t = threadIdx.x;
  if (t < 16) cnt[t] = 0;
  __syncthreads();
  for (int s = t; s < S; s += 256) atomicAdd(&cnt[sid[s]], 1);
  __syncthreads();
  if (t == 0) {
    int a = 0;
    for (int e = 0; e < 16; e++) { offs[e] = a; cur[e] = a; a += cnt[e]; }
    offs[16] = a;
  }
  __syncthreads();
  for (int s = t; s < S; s += 256) {
    int p = atomicAdd(&cur[sid[s]], 1);
    order[p] = s;
  }
}

// ---------------- expert 128x128x64 bf16 MFMA GEMM (m97-style, unchanged) ----------------
template <bool GATHER_A, bool SCATTER_C, bool GELU, bool OUT_F32>
__global__ __launch_bounds__(256) void gemm_mfma(
    const unsigned short* __restrict__ A, const unsigned short* __restrict__ BT,
    const float* __restrict__ bias, void* __restrict__ Cout,
    int M, int N, int K,
    const int* __restrict__ order, const int* __restrict__ offs,
    int S, long btStride, int biasStride) {
  const int t = (int)threadIdx.x;
  const int lane = t & 63;
  const int w = t >> 6;
  const int wm = w >> 1, wn = w & 1;
  const int tileN = (int)blockIdx.x, tileM = (int)blockIdx.y, e = (int)blockIdx.z;

  const int o0 = offs[e], o1 = offs[e + 1];
  const int rowBase = 4 * o0;
  const int Me = 4 * (o1 - o0);
  if (tileM * 128 >= Me) return;
  const unsigned short* bt = BT + (long)e * btStride;
  const float* bs = bias + (long)e * biasStride;

  __shared__ __align__(16) unsigned short lA[128 * 64];
  __shared__ __align__(16) unsigned short lB[128 * 64];

  const unsigned short* aSrc[4];
  const unsigned short* bSrc[4];
  {
    const int q = t & 7;
#pragma unroll
    for (int i = 0; i < 4; i++) {
      const int row = i * 32 + (t >> 3);
      const int koff = ((q * 16) ^ ((row & 7) << 4)) >> 1;
      long arow;
      const int lrow = tileM * 128 + row;
      const int rr = (lrow < Me) ? lrow : (Me - 1);
      const int g = rowBase + rr;
      if (GATHER_A) {
        const int s = order[g >> 2];
        arow = (long)(g & 3) * S + s;
      } else {
        arow = g;
      }
      aSrc[i] = A + arow * (long)K + koff;
      const int col = tileN * 128 + row;
      bSrc[i] = bt + (long)col * K + koff;
    }
  }

  f32x4 acc[4][4] = {};

  const int KT = K >> 6;
  for (int kt = 0; kt < KT; kt++) {
    __syncthreads();
#pragma unroll
    for (int i = 0; i < 4; i++) {
      gload_lds16(aSrc[i] + (kt << 6), (void*)(lA + i * 2048 + w * 512));
      gload_lds16(bSrc[i] + (kt << 6), (void*)(lB + i * 2048 + w * 512));
    }
    __syncthreads();
#pragma unroll
    for (int kk = 0; kk < 2; kk++) {
      short8 af[4], bfr[4];
      const int kbyte = kk * 64 + (lane >> 4) * 16;
#pragma unroll
      for (int mi = 0; mi < 4; mi++) {
        const int row = wm * 64 + mi * 16 + (lane & 15);
        const int off = row * 128 + (kbyte ^ ((row & 7) << 4));
        af[mi] = *(const short8*)((const char*)lA + off);
      }
#pragma unroll
      for (int ni = 0; ni < 4; ni++) {
        const int row = wn * 64 + ni * 16 + (lane & 15);
        const int off = row * 128 + (kbyte ^ ((row & 7) << 4));
        bfr[ni] = *(const short8*)((const char*)lB + off);
      }
#pragma unroll
      for (int mi = 0; mi < 4; mi++)
#pragma unroll
        for (int ni = 0; ni < 4; ni++)
          acc[mi][ni] = __builtin_amdgcn_mfma_f32_16x16x32_bf16(af[mi], bfr[ni], acc[mi][ni], 0, 0, 0);
    }
  }

  float bcol[4];
#pragma unroll
  for (int ni = 0; ni < 4; ni++)
    bcol[ni] = bs[tileN * 128 + wn * 64 + ni * 16 + (lane & 15)];

#pragma unroll
  for (int mi = 0; mi < 4; mi++) {
#pragma unroll
    for (int j = 0; j < 4; j++) {
      const int lrow = tileM * 128 + wm * 64 + mi * 16 + ((lane >> 4) * 4) + j;
      if (lrow >= Me) continue;
      const int g = rowBase + lrow;
      long crow;
      if (SCATTER_C) crow = (long)(g & 3) * S + order[g >> 2];
      else crow = g;
#pragma unroll
      for (int ni = 0; ni < 4; ni++) {
        float v = acc[mi][ni][j] + bcol[ni];
        if (GELU) v = gelu_exact(v);
        const long cidx = crow * (long)N + tileN * 128 + wn * 64 + ni * 16 + (lane & 15);
        if (OUT_F32) ((float*)Cout)[cidx] = v;
        else ((unsigned short*)Cout)[cidx] = f2bf(v);
      }
    }
  }
}

// ---------------- dense 256x256x64 GEMM, m201-style 8-phase schedule ----------------
// C[M][N] = A[M][K] @ BT[N][K]^T (+bias, opt GELU). M%256==0, N%256==0, K%128==0.
// 512 threads = 8 waves (2 along M x 4 along N); per-wave 128x64 output (8x4 frags).
// LDS: 8 half-buffers [d][mat][h] of 128x64 bf16 (16 KiB) = 128 KiB.
// Per K-tile: 4 quadrant phases; B-frags of both halves kept in registers.
// Each phase stages ONE half-buffer (2 x global_load_lds); stage slot is >=1 barrier
// after that half's last reader. vmcnt(6) at END of phases 3 and 7, BEFORE the phase
// barrier -> after that barrier ALL waves' halves for the next 4 phases are resident
// (3 half-tiles stay in flight, m201 discipline). NO sched_barrier / manual lgkmcnt
// in the loop: ds_reads are compiler-visible, and m141 showed order-pinning defeats
// the scheduler. Memory-op ordering across phases is enforced by the s_barrier asm.
template <bool GELU, bool OUT_F32>
__global__ __launch_bounds__(512, 2) void gemm_8phase(
    const unsigned short* __restrict__ A, const unsigned short* __restrict__ BT,
    const float* __restrict__ bias, void* __restrict__ Cout,
    int N, int K, int ntiles) {
  __shared__ __align__(16) unsigned short lds[8 * 8192];  // [d][mat][h][128*64]

  const int t = (int)threadIdx.x;
  const int lane = t & 63;
  const int w = t >> 6;
  const int wm = w >> 2;   // 0..1 (M half of tile)
  const int wn = w & 3;    // 0..3 (N quarter of tile)

  // XCD-chunked bijective swizzle (gridDim.x % 8 == 0), ntile fastest in chunk.
  const int cpx = (int)gridDim.x >> 3;
  const int swz = ((int)blockIdx.x & 7) * cpx + ((int)blockIdx.x >> 3);
  const int mtile = swz / ntiles, ntile = swz % ntiles;

  // Staging source pointers [i][h]; XOR swizzle (byte ^= (rowInHalf&7)<<4)
  // pre-applied to the global source column (both-sides rule).
  const int tq = t & 7;
  const unsigned short* srcA[2][2];
  const unsigned short* srcB[2][2];
#pragma unroll
  for (int i = 0; i < 2; i++) {
    const int ir = i * 64 + (t >> 3);                       // rowInHalf
    const int koffE = ((tq * 16) ^ ((ir & 7) << 4)) >> 1;   // element offset
#pragma unroll
    for (int h = 0; h < 2; h++) {
      const int ra = (ir & 63) + (h << 6) + ((ir >> 6) << 7);   // tile row
      srcA[i][h] = A + (long)(mtile * 256 + ra) * K + koffE;
      const int cb = (ir & 31) + (h << 5) + ((ir >> 5) << 6);   // tile col
      srcB[i][h] = BT + (long)(ntile * 256 + cb) * K + koffE;
    }
  }
  const int dstE = (t >> 3) * 64 + tq * 8;  // linear LDS dest (== base + lane*16B)

  auto STAGE = [&](int d, int mat, int h, int kt) {
    unsigned short* dst = lds + ((d * 4 + mat * 2 + h) << 13) + dstE;
    const unsigned short* s0 = (mat == 0 ? srcA[0][h] : srcB[0][h]) + (kt << 6);
    const unsigned short* s1 = (mat == 0 ? srcA[1][h] : srcB[1][h]) + (kt << 6);
    gload_lds16(s0, dst);
    gload_lds16(s1, dst + 4096);
  };

  short8 aReg[8], bReg[8];
  const int klane = (lane >> 4) << 4;
  const int rsw = (lane & 7) << 4;   // rowInHalf&7 == lane&7 for all frag reads

  auto LDA = [&](int d, int mh) {
    const char* base = (const char*)(lds + ((d * 4 + mh) << 13));
    const int r0 = wm * 64 + (lane & 15);
#pragma unroll
    for (int m = 0; m < 4; m++) {
      const int row = r0 + m * 16;
#pragma unroll
      for (int kk = 0; kk < 2; kk++)
        aReg[m * 2 + kk] = *(const short8*)(base + row * 128 + ((kk * 64 + klane) ^ rsw));
    }
  };
  auto LDB = [&](int d, int nh) {
    const char* base = (const char*)(lds + ((d * 4 + 2 + nh) << 13));
    const int r0 = wn * 32 + (lane & 15);
#pragma unroll
    for (int n = 0; n < 2; n++) {
      const int row = r0 + n * 16;
#pragma unroll
      for (int kk = 0; kk < 2; kk++)
        bReg[(nh * 2 + n) * 2 + kk] = *(const short8*)(base + row * 128 + ((kk * 64 + klane) ^ rsw));
    }
  };

  f32x4 acc[8][4] = {};
  auto MMA = [&](int mb, int nb) {   // 4 mi x 2 ni x 2 kk = 16 MFMA
    __builtin_amdgcn_s_setprio(1);
#pragma unroll
    for (int kk = 0; kk < 2; kk++)
#pragma unroll
      for (int m = 0; m < 4; m++)
#pragma unroll
        for (int n = 0; n < 2; n++)
          acc[mb + m][nb + n] = __builtin_amdgcn_mfma_f32_16x16x32_bf16(
              aReg[m * 2 + kk], bReg[(nb + n) * 2 + kk], acc[mb + m][nb + n], 0, 0, 0);
    __builtin_amdgcn_s_setprio(0);
  };

  const int KT = K >> 6;

  // Prologue: buf0 <- tile0 (all 4 halves); buf1 <- tile1 (A0,B0,B1; A1 comes at p0).
  {
    const int t1 = (KT > 1) ? 1 : 0;
    STAGE(0, 0, 0, 0); STAGE(0, 1, 0, 0); STAGE(0, 1, 1, 0); STAGE(0, 0, 1, 0);
    STAGE(1, 0, 0, t1); STAGE(1, 1, 0, t1); STAGE(1, 1, 1, t1);
    VMW(6);            // 14 outstanding -> oldest 8 (all of tile0) done
    BARRIER();
  }

  for (int it = 0; it < (KT >> 1); ++it) {
    const int tb = (2 * it + 1 < KT) ? 2 * it + 1 : KT - 1;
    int nx = 2 * it + 2; if (nx >= KT) nx = KT - 1;
    int ny = 2 * it + 3; if (ny >= KT) ny = KT - 1;
    // ---- p0: quadrant (0,0) of buf0 ----
    LDA(0, 0); LDB(0, 0); STAGE(1, 0, 1, tb);
    BARRIER();
    MMA(0, 0);
    BARRIER();
    // ---- p1: (0,1) ----
    LDB(0, 1); STAGE(0, 0, 0, nx);
    BARRIER();
    MMA(0, 2);
    BARRIER();
    // ---- p2: (1,0) ----
    LDA(0, 1); STAGE(0, 1, 0, nx);
    BARRIER();
    MMA(4, 0);
    BARRIER();
    // ---- p3: (1,1) ----
    STAGE(0, 1, 1, nx);
    BARRIER();
    MMA(4, 2);
    VMW(6);            // oldest 8 retired = all 4 buf1 halves needed by p4-p7
    BARRIER();
    // ---- p4: quadrant (0,0) of buf1 ----
    LDA(1, 0); LDB(1, 0); STAGE(0, 0, 1, nx);
    BARRIER();
    MMA(0, 0);
    BARRIER();
    // ---- p5: (0,1) ----
    LDB(1, 1); STAGE(1, 0, 0, ny);
    BARRIER();
    MMA(0, 2);
    BARRIER();
    // ---- p6: (1,0) ----
    LDA(1, 1); STAGE(1, 1, 0, ny);
    BARRIER();
    MMA(4, 0);
    BARRIER();
    // ---- p7: (1,1) ----
    STAGE(1, 1, 1, ny);
    BARRIER();
    MMA(4, 2);
    VMW(6);            // oldest 8 retired = all 4 buf0 halves for next iteration
    BARRIER();
  }
  VMW(0);              // drain trailing prefetches before epilogue

  // Epilogue. C/D layout: col = lane&15, row = (lane>>4)*4 + reg.
  float bcol[4];
#pragma unroll
  for (int n = 0; n < 4; n++)
    bcol[n] = bias[ntile * 256 + wn * 64 + n * 16 + (lane & 15)];
  const int cbase = ntile * 256 + wn * 64 + (lane & 15);
#pragma unroll
  for (int m = 0; m < 8; m++) {
#pragma unroll
    for (int j = 0; j < 4; j++) {
      const long crow = mtile * 256 + wm * 128 + m * 16 + ((lane >> 4) << 2) + j;
#pragma unroll
      for (int n = 0; n < 4; n++) {
        float v = acc[m][n][j] + bcol[n];
        if (GELU) v = gelu_exact(v);
        const long cidx = crow * (long)N + cbase + n * 16;
        if (OUT_F32) ((float*)Cout)[cidx] = v;
        else ((unsigned short*)Cout)[cidx] = f2bf(v);
      }
    }
  }
}

extern "C" void kernel_launch(void* const* d_in, const int* in_sizes, int n_in,
                              void* d_out, int out_size, void* d_ws, size_t ws_size,
                              hipStream_t stream) {
  const float* x   = (const float*)d_in[0];
  const int*   sid = (const int*)d_in[1];
  const float* W1  = (const float*)d_in[2];
  const float* b1  = (const float*)d_in[3];
  const float* W2  = (const float*)d_in[4];
  const float* b2  = (const float*)d_in[5];
  const float* Wg1 = (const float*)d_in[6];
  const float* bg1 = (const float*)d_in[7];
  const float* Wg2 = (const float*)d_in[8];
  const float* bg2 = (const float*)d_in[9];
  (void)in_sizes; (void)n_in; (void)out_size; (void)ws_size;

  constexpr int E = 16, D = 1024, H = 256, S = 4096, B = 4;
  constexpr long NT = (long)B * S;  // 16384 token rows

  char* ws = (char*)d_ws;
  unsigned short* xb   = (unsigned short*)(ws);
  unsigned short* w1t  = (unsigned short*)(ws + 33554432);
  unsigned short* w2t  = (unsigned short*)(ws + 41943040);
  unsigned short* wg1t = (unsigned short*)(ws + 50331648);
  unsigned short* wg2t = (unsigned short*)(ws + 52428800);
  unsigned short* hbuf = (unsigned short*)(ws + 54525952);
  unsigned short* rout = (unsigned short*)(ws + 62914560);
  int* offs  = (int*)(ws + 96468992);
  int* order = (int*)(ws + 96469248);

  cast_bf16_kernel<<<dim3((unsigned)(NT * D / 2048)), 256, 0, stream>>>(x, xb, NT * D);
  tcast_kernel<<<dim3(H / 64, D / 64, E), 256, 0, stream>>>(W1, w1t, D, H, (long)D * H);
  tcast_kernel<<<dim3(D / 64, H / 64, E), 256, 0, stream>>>(W2, w2t, H, D, (long)D * H);
  tcast_kernel<<<dim3(D / 64, D / 64, 1), 256, 0, stream>>>(Wg1, wg1t, D, D, (long)D * D);
  tcast_kernel<<<dim3(D / 64, D / 64, 1), 256, 0, stream>>>(Wg2, wg2t, D, D, (long)D * D);
  route_kernel<<<1, 256, 0, stream>>>(sid, S, offs, order);

  // GEMM1: h = gelu(gather(x) @ W1[e] + b1[e])   [sorted rows, bf16]
  gemm_mfma<true, false, true, false><<<dim3(H / 128, 128, E), 256, 0, stream>>>(
      xb, w1t, b1, hbuf, (int)NT, H, D, order, offs, S, (long)H * D, H);
  // GEMM2: routed = h @ W2[e] + b2[e]            [scatter to natural rows, bf16]
  gemm_mfma<false, true, false, false><<<dim3(D / 128, 128, E), 256, 0, stream>>>(
      hbuf, w2t, b2, rout, (int)NT, D, H, order, offs, S, (long)D * H, D);
  // GEMM3: g = gelu(routed @ Wg1 + bg1)          [bf16, reuses xb buffer]
  gemm_8phase<true, false><<<dim3((unsigned)(NT / 256) * (D / 256)), 512, 0, stream>>>(
      rout, wg1t, bg1, xb, D, D, D / 256);
  // GEMM4: out = g @ Wg2 + bg2                   [fp32 to d_out]
  gemm_8phase<false, true><<<dim3((unsigned)(NT / 256) * (D / 256)), 512, 0, stream>>>(
      xb, wg2t, bg2, d_out, D, D, D / 256);
}

// Round 5
// 194.573 us; speedup vs baseline: 1.0095x; 1.0095x over previous
//
#include <hip/hip_runtime.h>

// SplatAwareFeedForward on MI355X (gfx950).
// Pipeline: prep (cast+transposes, 1 launch) -> route (tile lists) ->
//           expert GEMMs (m97-style, compact grids) ->
//           dense aggregator GEMMs (256x256x64, 8-phase, 32x32x16 MFMA).
// Workspace layout (bytes):
//   xb    @ 0        : 33,554,432  (B*S*D bf16; reused as g-buffer for GEMM4 input)
//   w1t   @ 33554432 :  8,388,608  (E*[H][D] bf16, transposed W1)
//   w2t   @ 41943040 :  8,388,608  (E*[D][H] bf16, transposed W2)
//   wg1t  @ 50331648 :  2,097,152  ([D][D] bf16, transposed Wg1)
//   wg2t  @ 52428800 :  2,097,152  ([D][D] bf16, transposed Wg2)
//   hbuf  @ 54525952 :  8,388,608  (B*S*H bf16, expert-sorted hidden)
//   rout  @ 62914560 : 33,554,432  (B*S*D bf16, routed output, natural order)
//   offs  @ 96468992 : 68          (E+1 ints)
//   order @ 96469248 : 16,384      (S ints sorted by expert)
//   tileE @ 96485632 : 576         (expert id per row-tile, <=144)
//   tileR @ 96486208 : 576         (sorted-row start per row-tile)
//   ntl   @ 96486784 : 4           (tile count)

#define DEV __device__ __forceinline__

typedef float f32x4 __attribute__((ext_vector_type(4)));
typedef float f32x16 __attribute__((ext_vector_type(16)));
typedef short short8 __attribute__((ext_vector_type(8)));

DEV unsigned short f2bf(float f) {
  unsigned u = __float_as_uint(f);
  u += 0x7fffu + ((u >> 16) & 1u);   // round-to-nearest-even
  return (unsigned short)(u >> 16);
}

DEV void gload_lds16(const void* g, void* l) {
  __builtin_amdgcn_global_load_lds(
      (const __attribute__((address_space(1))) unsigned int*)g,
      (__attribute__((address_space(3))) unsigned int*)l, 16, 0, 0);
}

DEV float gelu_exact(float v) {
  return 0.5f * v * (1.0f + erff(v * 0.70710678118654752f));
}

#define BARRIER() __builtin_amdgcn_s_barrier()
#define VMW(n)    asm volatile("s_waitcnt vmcnt(" #n ")" ::: "memory")

// ---------------- prep: x-cast + all transpose-casts in ONE launch ----------------
// blocks [0,8192): cast x (16M f32 -> bf16, 2048 elems/block)
// blocks [8192,9216): W1 tiles (E=16 x 64 tiles of 64x64, R=1024,C=256)
// blocks [9216,10240): W2 tiles (E=16 x 64, R=256,C=1024)
// blocks [10240,10496): Wg1 (256 tiles, 1024x1024)
// blocks [10496,10752): Wg2
__global__ __launch_bounds__(256) void prep_kernel(
    const float* __restrict__ x, unsigned short* __restrict__ xb,
    const float* __restrict__ W1, unsigned short* __restrict__ w1t,
    const float* __restrict__ W2, unsigned short* __restrict__ w2t,
    const float* __restrict__ Wg1, unsigned short* __restrict__ wg1t,
    const float* __restrict__ Wg2, unsigned short* __restrict__ wg2t) {
  __shared__ float tile[64][65];
  const int t = threadIdx.x;
  int id = (int)blockIdx.x;
  if (id < 8192) {
    long i = ((long)id * 256 + t) * 8;
    float4 v0 = *(const float4*)(x + i);
    float4 v1 = *(const float4*)(x + i + 4);
    uint4 o;
    o.x = (unsigned)f2bf(v0.x) | ((unsigned)f2bf(v0.y) << 16);
    o.y = (unsigned)f2bf(v0.z) | ((unsigned)f2bf(v0.w) << 16);
    o.z = (unsigned)f2bf(v1.x) | ((unsigned)f2bf(v1.y) << 16);
    o.w = (unsigned)f2bf(v1.z) | ((unsigned)f2bf(v1.w) << 16);
    *(uint4*)(xb + i) = o;
    return;
  }
  id -= 8192;
  const float* in; unsigned short* out;
  int R, C, r0, c0; long base;
  if (id < 1024) {          // W1: [1024][256] -> [256][1024] per expert
    in = W1; out = w1t; R = 1024; C = 256;
    base = (long)(id >> 6) * 262144;
    r0 = ((id >> 2) & 15) * 64; c0 = (id & 3) * 64;
  } else if (id < 2048) {   // W2: [256][1024] -> [1024][256] per expert
    id -= 1024;
    in = W2; out = w2t; R = 256; C = 1024;
    base = (long)(id >> 6) * 262144;
    r0 = ((id >> 4) & 3) * 64; c0 = (id & 15) * 64;
  } else if (id < 2304) {   // Wg1: [1024][1024]
    id -= 2048;
    in = Wg1; out = wg1t; R = 1024; C = 1024; base = 0;
    r0 = (id >> 4) * 64; c0 = (id & 15) * 64;
  } else {                  // Wg2
    id -= 2304;
    in = Wg2; out = wg2t; R = 1024; C = 1024; base = 0;
    r0 = (id >> 4) * 64; c0 = (id & 15) * 64;
  }
  const int cc = t & 63, rr = t >> 6;
#pragma unroll
  for (int i = 0; i < 16; i++) {
    int r = rr + i * 4;
    tile[r][cc] = in[base + (long)(r0 + r) * C + (c0 + cc)];
  }
  __syncthreads();
#pragma unroll
  for (int i = 0; i < 16; i++) {
    int c = rr + i * 4;
    out[base + (long)(c0 + c) * R + (r0 + cc)] = f2bf(tile[cc][c]);
  }
}

// ---------------- routing: counts -> prefix -> sorted order -> row-tile list ----------------
__global__ __launch_bounds__(256) void route_kernel(
    const int* __restrict__ sid, int S, int* __restrict__ offs, int* __restrict__ order,
    int* __restrict__ tileE, int* __restrict__ tileR, int* __restrict__ ntl) {
  __shared__ int cnt[16], cur[16];
  const int t = threadIdx.x;
  if (t < 16) cnt[t] = 0;
  __syncthreads();
  for (int s = t; s < S; s += 256) atomicAdd(&cnt[sid[s]], 1);
  __syncthreads();
  if (t == 0) {
    int a = 0;
    for (int e = 0; e < 16; e++) { offs[e] = a; cur[e] = a; a += cnt[e]; }
    offs[16] = a;
    int nt = 0;
    for (int e = 0; e < 16; e++) {
      const int rows = 4 * cnt[e];
      for (int r = 0; r < rows; r += 128) {
        tileE[nt] = e;
        tileR[nt] = 4 * offs[e] + r;
        nt++;
      }
    }
    ntl[0] = nt;
  }
  __syncthreads();
  for (int s = t; s < S; s += 256) {
    int p = atomicAdd(&cur[sid[s]], 1);
    order[p] = s;
  }
}

// ---------------- expert 128x128x64 bf16 MFMA GEMM (m97-style, compact tile grid) ----------------
template <bool GATHER_A, bool SCATTER_C, bool GELU, bool OUT_F32>
__global__ __launch_bounds__(256) void gemm_mfma(
    const unsigned short* __restrict__ A, const unsigned short* __restrict__ BT,
    const float* __restrict__ bias, void* __restrict__ Cout,
    int N, int K,
    const int* __restrict__ order, const int* __restrict__ offs,
    const int* __restrict__ tileE, const int* __restrict__ tileR,
    const int* __restrict__ ntl,
    int S, long btStride, int biasStride) {
  const int ti = (int)blockIdx.y;
  if (ti >= ntl[0]) return;
  const int t = (int)threadIdx.x;
  const int lane = t & 63;
  const int w = t >> 6;
  const int wm = w >> 1, wn = w & 1;
  const int tileN = (int)blockIdx.x;

  const int e = tileE[ti];
  const int rowBase = tileR[ti];
  int Me = 4 * offs[e + 1] - rowBase;
  if (Me > 128) Me = 128;
  const unsigned short* bt = BT + (long)e * btStride;
  const float* bs = bias + (long)e * biasStride;

  __shared__ __align__(16) unsigned short lA[128 * 64];
  __shared__ __align__(16) unsigned short lB[128 * 64];

  const unsigned short* aSrc[4];
  const unsigned short* bSrc[4];
  {
    const int q = t & 7;
#pragma unroll
    for (int i = 0; i < 4; i++) {
      const int row = i * 32 + (t >> 3);
      const int koff = ((q * 16) ^ ((row & 7) << 4)) >> 1;
      const int rr = (row < Me) ? row : (Me - 1);
      const int g = rowBase + rr;
      long arow;
      if (GATHER_A) {
        const int s = order[g >> 2];
        arow = (long)(g & 3) * S + s;
      } else {
        arow = g;
      }
      aSrc[i] = A + arow * (long)K + koff;
      const int col = tileN * 128 + row;
      bSrc[i] = bt + (long)col * K + koff;
    }
  }

  f32x4 acc[4][4] = {};

  const int KT = K >> 6;
  for (int kt = 0; kt < KT; kt++) {
    __syncthreads();
#pragma unroll
    for (int i = 0; i < 4; i++) {
      gload_lds16(aSrc[i] + (kt << 6), (void*)(lA + i * 2048 + w * 512));
      gload_lds16(bSrc[i] + (kt << 6), (void*)(lB + i * 2048 + w * 512));
    }
    __syncthreads();
#pragma unroll
    for (int kk = 0; kk < 2; kk++) {
      short8 af[4], bfr[4];
      const int kbyte = kk * 64 + (lane >> 4) * 16;
#pragma unroll
      for (int mi = 0; mi < 4; mi++) {
        const int row = wm * 64 + mi * 16 + (lane & 15);
        const int off = row * 128 + (kbyte ^ ((row & 7) << 4));
        af[mi] = *(const short8*)((const char*)lA + off);
      }
#pragma unroll
      for (int ni = 0; ni < 4; ni++) {
        const int row = wn * 64 + ni * 16 + (lane & 15);
        const int off = row * 128 + (kbyte ^ ((row & 7) << 4));
        bfr[ni] = *(const short8*)((const char*)lB + off);
      }
#pragma unroll
      for (int mi = 0; mi < 4; mi++)
#pragma unroll
        for (int ni = 0; ni < 4; ni++)
          acc[mi][ni] = __builtin_amdgcn_mfma_f32_16x16x32_bf16(af[mi], bfr[ni], acc[mi][ni], 0, 0, 0);
    }
  }

  float bcol[4];
#pragma unroll
  for (int ni = 0; ni < 4; ni++)
    bcol[ni] = bs[tileN * 128 + wn * 64 + ni * 16 + (lane & 15)];

#pragma unroll
  for (int mi = 0; mi < 4; mi++) {
#pragma unroll
    for (int j = 0; j < 4; j++) {
      const int lrow = wm * 64 + mi * 16 + ((lane >> 4) * 4) + j;
      if (lrow >= Me) continue;
      const int g = rowBase + lrow;
      long crow;
      if (SCATTER_C) crow = (long)(g & 3) * S + order[g >> 2];
      else crow = g;
#pragma unroll
      for (int ni = 0; ni < 4; ni++) {
        float v = acc[mi][ni][j] + bcol[ni];
        if (GELU) v = gelu_exact(v);
        const long cidx = crow * (long)N + tileN * 128 + wn * 64 + ni * 16 + (lane & 15);
        if (OUT_F32) ((float*)Cout)[cidx] = v;
        else ((unsigned short*)Cout)[cidx] = f2bf(v);
      }
    }
  }
}

// ---------------- dense 256x256x64 GEMM, 8-phase schedule, 32x32x16 MFMA ----------------
// Same schedule/LDS/staging as round 3/4 (verified correct); only the compute
// fragment shape changes: per wave 4x2 frags of 32x32, 8 MFMA per phase (half
// the instruction count of the 16x16 version -> tests per-MFMA overhead).
template <bool GELU, bool OUT_F32>
__global__ __launch_bounds__(512, 2) void gemm_8p32(
    const unsigned short* __restrict__ A, const unsigned short* __restrict__ BT,
    const float* __restrict__ bias, void* __restrict__ Cout,
    int N, int K, int ntiles) {
  __shared__ __align__(16) unsigned short lds[8 * 8192];  // [d][mat][h][128*64]

  const int t = (int)threadIdx.x;
  const int lane = t & 63;
  const int w = t >> 6;
  const int wm = w >> 2;   // 0..1 (M half of tile)
  const int wn = w & 3;    // 0..3 (N quarter of tile)

  // XCD-chunked bijective swizzle (gridDim.x % 8 == 0), ntile fastest in chunk.
  const int cpx = (int)gridDim.x >> 3;
  const int swz = ((int)blockIdx.x & 7) * cpx + ((int)blockIdx.x >> 3);
  const int mtile = swz / ntiles, ntile = swz % ntiles;

  // Staging (identical to prior rounds). XOR swizzle (byte ^= (rowInHalf&7)<<4)
  // pre-applied to global source column.
  const int tq = t & 7;
  const unsigned short* srcA[2][2];
  const unsigned short* srcB[2][2];
#pragma unroll
  for (int i = 0; i < 2; i++) {
    const int ir = i * 64 + (t >> 3);                       // rowInHalf
    const int koffE = ((tq * 16) ^ ((ir & 7) << 4)) >> 1;
#pragma unroll
    for (int h = 0; h < 2; h++) {
      const int ra = (ir & 63) + (h << 6) + ((ir >> 6) << 7);   // tile row
      srcA[i][h] = A + (long)(mtile * 256 + ra) * K + koffE;
      const int cb = (ir & 31) + (h << 5) + ((ir >> 5) << 6);   // tile col
      srcB[i][h] = BT + (long)(ntile * 256 + cb) * K + koffE;
    }
  }
  const int dstE = (t >> 3) * 64 + tq * 8;

  auto STAGE = [&](int d, int mat, int h, int kt) {
    unsigned short* dst = lds + ((d * 4 + mat * 2 + h) << 13) + dstE;
    const unsigned short* s0 = (mat == 0 ? srcA[0][h] : srcB[0][h]) + (kt << 6);
    const unsigned short* s1 = (mat == 0 ? srcA[1][h] : srcB[1][h]) + (kt << 6);
    gload_lds16(s0, dst);
    gload_lds16(s1, dst + 4096);
  };

  // Fragment reads for 32x32x16: lane holds row (lane&31), k = (lane>>5)*8 + j.
  // Byte col for k-step kk: kk*32 + (lane>>5)*16, XORed with (row&7)<<4.
  short8 aR[2][4], bR[2][4];
  const int kcol = ((lane >> 5) << 4);
  const int l31 = lane & 31;

  auto LDA = [&](int d, int mh) {
    const char* base = (const char*)(lds + ((d * 4 + mh) << 13));
    const int r0 = wm * 64 + l31;           // rowInHalf base for this wave/quadrant
#pragma unroll
    for (int m = 0; m < 2; m++) {
      const int row = r0 + m * 32;
      const int rs = (row & 7) << 4;
#pragma unroll
      for (int kk = 0; kk < 4; kk++)
        aR[m][kk] = *(const short8*)(base + row * 128 + ((kk * 32 + kcol) ^ rs));
    }
  };
  auto LDB = [&](int d, int nh) {
    const char* base = (const char*)(lds + ((d * 4 + 2 + nh) << 13));
    const int col = wn * 32 + l31;          // colInHalf for this wave/quadrant
    const int rs = (col & 7) << 4;
#pragma unroll
    for (int kk = 0; kk < 4; kk++)
      bR[nh][kk] = *(const short8*)(base + col * 128 + ((kk * 32 + kcol) ^ rs));
  };

  f32x16 acc[4][2] = {};
  auto MMA = [&](int mh, int nh) {   // 2 m x 4 kk = 8 MFMA of 32x32x16
    __builtin_amdgcn_s_setprio(1);
#pragma unroll
    for (int kk = 0; kk < 4; kk++)
#pragma unroll
      for (int m = 0; m < 2; m++)
        acc[mh * 2 + m][nh] = __builtin_amdgcn_mfma_f32_32x32x16_bf16(
            aR[m][kk], bR[nh][kk], acc[mh * 2 + m][nh], 0, 0, 0);
    __builtin_amdgcn_s_setprio(0);
  };

  const int KT = K >> 6;

  // Prologue: buf0 <- tile0 (all 4 halves); buf1 <- tile1 (A0,B0,B1; A1 at p0).
  {
    const int t1 = (KT > 1) ? 1 : 0;
    STAGE(0, 0, 0, 0); STAGE(0, 1, 0, 0); STAGE(0, 1, 1, 0); STAGE(0, 0, 1, 0);
    STAGE(1, 0, 0, t1); STAGE(1, 1, 0, t1); STAGE(1, 1, 1, t1);
    VMW(6);
    BARRIER();
  }

  for (int it = 0; it < (KT >> 1); ++it) {
    const int tb = (2 * it + 1 < KT) ? 2 * it + 1 : KT - 1;
    int nx = 2 * it + 2; if (nx >= KT) nx = KT - 1;
    int ny = 2 * it + 3; if (ny >= KT) ny = KT - 1;
    // ---- p0: quadrant (0,0) of buf0 ----
    LDA(0, 0); LDB(0, 0); STAGE(1, 0, 1, tb);
    BARRIER();
    MMA(0, 0);
    BARRIER();
    // ---- p1: (0,1) ----
    LDB(0, 1); STAGE(0, 0, 0, nx);
    BARRIER();
    MMA(0, 1);
    BARRIER();
    // ---- p2: (1,0) ----
    LDA(0, 1); STAGE(0, 1, 0, nx);
    BARRIER();
    MMA(1, 0);
    BARRIER();
    // ---- p3: (1,1) ----
    STAGE(0, 1, 1, nx);
    BARRIER();
    MMA(1, 1);
    VMW(6);
    BARRIER();
    // ---- p4: quadrant (0,0) of buf1 ----
    LDA(1, 0); LDB(1, 0); STAGE(0, 0, 1, nx);
    BARRIER();
    MMA(0, 0);
    BARRIER();
    // ---- p5: (0,1) ----
    LDB(1, 1); STAGE(1, 0, 0, ny);
    BARRIER();
    MMA(0, 1);
    BARRIER();
    // ---- p6: (1,0) ----
    LDA(1, 1); STAGE(1, 1, 0, ny);
    BARRIER();
    MMA(1, 0);
    BARRIER();
    // ---- p7: (1,1) ----
    STAGE(1, 1, 1, ny);
    BARRIER();
    MMA(1, 1);
    VMW(6);
    BARRIER();
  }
  VMW(0);

  // Epilogue. 32x32 C/D layout (HW-verified m74/m101):
  //   col = lane&31, row = (reg&3) + 8*(reg>>2) + 4*(lane>>5), reg in [0,16).
  float bc[2];
#pragma unroll
  for (int n = 0; n < 2; n++)
    bc[n] = bias[ntile * 256 + wn * 64 + n * 32 + l31];
  const int cbase = ntile * 256 + wn * 64 + l31;
  const int rbase = mtile * 256 + wm * 128 + ((lane >> 5) << 2);
#pragma unroll
  for (int mf = 0; mf < 4; mf++) {
#pragma unroll
    for (int reg = 0; reg < 16; reg++) {
      const long crow = rbase + mf * 32 + (reg & 3) + ((reg >> 2) << 3);
#pragma unroll
      for (int nf = 0; nf < 2; nf++) {
        float v = acc[mf][nf][reg] + bc[nf];
        if (GELU) v = gelu_exact(v);
        const long cidx = crow * (long)N + cbase + nf * 32;
        if (OUT_F32) ((float*)Cout)[cidx] = v;
        else ((unsigned short*)Cout)[cidx] = f2bf(v);
      }
    }
  }
}

extern "C" void kernel_launch(void* const* d_in, const int* in_sizes, int n_in,
                              void* d_out, int out_size, void* d_ws, size_t ws_size,
                              hipStream_t stream) {
  const float* x   = (const float*)d_in[0];
  const int*   sid = (const int*)d_in[1];
  const float* W1  = (const float*)d_in[2];
  const float* b1  = (const float*)d_in[3];
  const float* W2  = (const float*)d_in[4];
  const float* b2  = (const float*)d_in[5];
  const float* Wg1 = (const float*)d_in[6];
  const float* bg1 = (const float*)d_in[7];
  const float* Wg2 = (const float*)d_in[8];
  const float* bg2 = (const float*)d_in[9];
  (void)in_sizes; (void)n_in; (void)out_size; (void)ws_size;

  constexpr int D = 1024, H = 256, S = 4096, B = 4;
  constexpr long NT = (long)B * S;  // 16384 token rows

  char* ws = (char*)d_ws;
  unsigned short* xb   = (unsigned short*)(ws);
  unsigned short* w1t  = (unsigned short*)(ws + 33554432);
  unsigned short* w2t  = (unsigned short*)(ws + 41943040);
  unsigned short* wg1t = (unsigned short*)(ws + 50331648);
  unsigned short* wg2t = (unsigned short*)(ws + 52428800);
  unsigned short* hbuf = (unsigned short*)(ws + 54525952);
  unsigned short* rout = (unsigned short*)(ws + 62914560);
  int* offs  = (int*)(ws + 96468992);
  int* order = (int*)(ws + 96469248);
  int* tileE = (int*)(ws + 96485632);
  int* tileR = (int*)(ws + 96486208);
  int* ntl   = (int*)(ws + 96486784);

  prep_kernel<<<dim3(10752), 256, 0, stream>>>(x, xb, W1, w1t, W2, w2t, Wg1, wg1t, Wg2, wg2t);
  route_kernel<<<1, 256, 0, stream>>>(sid, S, offs, order, tileE, tileR, ntl);

  // GEMM1: h = gelu(gather(x) @ W1[e] + b1[e])   [sorted rows, bf16]
  gemm_mfma<true, false, true, false><<<dim3(H / 128, 144), 256, 0, stream>>>(
      xb, w1t, b1, hbuf, H, D, order, offs, tileE, tileR, ntl, S, (long)H * D, H);
  // GEMM2: routed = h @ W2[e] + b2[e]            [scatter to natural rows, bf16]
  gemm_mfma<false, true, false, false><<<dim3(D / 128, 144), 256, 0, stream>>>(
      hbuf, w2t, b2, rout, D, H, order, offs, tileE, tileR, ntl, S, (long)D * H, D);
  // GEMM3: g = gelu(routed @ Wg1 + bg1)          [bf16, reuses xb buffer]
  gemm_8p32<true, false><<<dim3((unsigned)(NT / 256) * (D / 256)), 512, 0, stream>>>(
      rout, wg1t, bg1, xb, D, D, D / 256);
  // GEMM4: out = g @ Wg2 + bg2                   [fp32 to d_out]
  gemm_8p32<false, true><<<dim3((unsigned)(NT / 256) * (D / 256)), 512, 0, stream>>>(
      xb, wg2t, bg2, d_out, D, D, D / 256);
}

// Round 7
// 182.028 us; speedup vs baseline: 1.0791x; 1.0689x over previous
//
#include <hip/hip_runtime.h>

// SplatAwareFeedForward on MI355X (gfx950).
// Pipeline: prep (weight transposes) -> route (64-row tile list) ->
//           fused expert kernel (gather+cast x -> GEMM1 -> h in LDS -> GEMM2 -> scatter) ->
//           dense GEMM3 (2-phase recipe, A/B test) -> dense GEMM4 (8-phase, control).
// Workspace layout (bytes):
//   g     @ 0        : 33,554,432  (B*S*D bf16; GEMM3 out / GEMM4 in)
//   w1t   @ 33554432 :  8,388,608  (E*[H][D] bf16, transposed W1)
//   w2t   @ 41943040 :  8,388,608  (E*[D][H] bf16, transposed W2)
//   wg1t  @ 50331648 :  2,097,152  ([D][D] bf16, transposed Wg1)
//   wg2t  @ 52428800 :  2,097,152  ([D][D] bf16, transposed Wg2)
//   rout  @ 62914560 : 33,554,432  (B*S*D bf16, routed output, natural order)
//   offs  @ 96468992 : 68          (E+1 ints)
//   order @ 96469248 : 16,384      (S ints sorted by expert)
//   tileE @ 96485632 : 1,280       (expert id per 64-row tile, <=272)
//   tileR @ 96486912 : 1,280       (sorted-row start per tile)
//   ntl   @ 96488192 : 4           (tile count)

#define DEV __device__ __forceinline__

typedef float f32x4 __attribute__((ext_vector_type(4)));
typedef short short8 __attribute__((ext_vector_type(8)));

DEV unsigned short f2bf(float f) {
  unsigned u = __float_as_uint(f);
  u += 0x7fffu + ((u >> 16) & 1u);   // round-to-nearest-even
  return (unsigned short)(u >> 16);
}

DEV void gload16(const void* g, void* l) {
  __builtin_amdgcn_global_load_lds(
      (const __attribute__((address_space(1))) unsigned int*)g,
      (__attribute__((address_space(3))) unsigned int*)l, 16, 0, 0);
}

DEV float gelu_exact(float v) {
  return 0.5f * v * (1.0f + erff(v * 0.70710678118654752f));
}

#define BARRIER() __builtin_amdgcn_s_barrier()
#define VMW(n)    asm volatile("s_waitcnt vmcnt(" #n ")" ::: "memory")

// ---------------- prep: weight transpose-casts only ----------------
// blocks [0,1024): W1 (E=16 x 64 tiles, R=1024,C=256)
// blocks [1024,2048): W2 (E=16 x 64, R=256,C=1024)
// blocks [2048,2304): Wg1 (256 tiles, 1024x1024); [2304,2560): Wg2
__global__ __launch_bounds__(256) void prep_kernel(
    const float* __restrict__ W1, unsigned short* __restrict__ w1t,
    const float* __restrict__ W2, unsigned short* __restrict__ w2t,
    const float* __restrict__ Wg1, unsigned short* __restrict__ wg1t,
    const float* __restrict__ Wg2, unsigned short* __restrict__ wg2t) {
  __shared__ float tile[64][65];
  const int t = threadIdx.x;
  int id = (int)blockIdx.x;
  const float* in; unsigned short* out;
  int R, C, r0, c0; long base;
  if (id < 1024) {
    in = W1; out = w1t; R = 1024; C = 256;
    base = (long)(id >> 6) * 262144;
    r0 = ((id >> 2) & 15) * 64; c0 = (id & 3) * 64;
  } else if (id < 2048) {
    id -= 1024;
    in = W2; out = w2t; R = 256; C = 1024;
    base = (long)(id >> 6) * 262144;
    r0 = ((id >> 4) & 3) * 64; c0 = (id & 15) * 64;
  } else if (id < 2304) {
    id -= 2048;
    in = Wg1; out = wg1t; R = 1024; C = 1024; base = 0;
    r0 = (id >> 4) * 64; c0 = (id & 15) * 64;
  } else {
    id -= 2304;
    in = Wg2; out = wg2t; R = 1024; C = 1024; base = 0;
    r0 = (id >> 4) * 64; c0 = (id & 15) * 64;
  }
  const int cc = t & 63, rr = t >> 6;
#pragma unroll
  for (int i = 0; i < 16; i++) {
    int r = rr + i * 4;
    tile[r][cc] = in[base + (long)(r0 + r) * C + (c0 + cc)];
  }
  __syncthreads();
#pragma unroll
  for (int i = 0; i < 16; i++) {
    int c = rr + i * 4;
    out[base + (long)(c0 + c) * R + (r0 + cc)] = f2bf(tile[cc][c]);
  }
}

// ---------------- routing: counts -> prefix -> sorted order -> 64-row tile list ----------------
__global__ __launch_bounds__(256) void route_kernel(
    const int* __restrict__ sid, int S, int* __restrict__ offs, int* __restrict__ order,
    int* __restrict__ tileE, int* __restrict__ tileR, int* __restrict__ ntl) {
  __shared__ int cnt[16], cur[16];
  const int t = threadIdx.x;
  if (t < 16) cnt[t] = 0;
  __syncthreads();
  for (int s = t; s < S; s += 256) atomicAdd(&cnt[sid[s]], 1);
  __syncthreads();
  if (t == 0) {
    int a = 0;
    for (int e = 0; e < 16; e++) { offs[e] = a; cur[e] = a; a += cnt[e]; }
    offs[16] = a;
    int nt = 0;
    for (int e = 0; e < 16; e++) {
      const int rows = 4 * cnt[e];
      for (int r = 0; r < rows; r += 64) {
        tileE[nt] = e;
        tileR[nt] = 4 * offs[e] + r;
        nt++;
      }
    }
    ntl[0] = nt;
  }
  __syncthreads();
  for (int s = t; s < S; s += 256) {
    int p = atomicAdd(&cur[sid[s]], 1);
    order[p] = s;
  }
}

// ---------------- fused expert kernel ----------------
// Per block: 64 sorted token-rows of expert e.
// Phase A: h[64][256] = gelu(gather(x,f32->bf16) @ W1[e] + b1[e]), h kept in LDS.
// Phase B: rout[scatter rows][1024] = h @ W2[e] + b2[e].
// 512 threads = 8 waves (2M x 4N). LDS: lA 8KB + lB 32KB + hS 32KB = 72KB (2 blocks/CU).
__global__ __launch_bounds__(512, 2) void fused_expert(
    const float* __restrict__ x,
    const unsigned short* __restrict__ w1t, const float* __restrict__ b1,
    const unsigned short* __restrict__ w2t, const float* __restrict__ b2,
    unsigned short* __restrict__ rout,
    const int* __restrict__ order, const int* __restrict__ offs,
    const int* __restrict__ tileE, const int* __restrict__ tileR,
    const int* __restrict__ ntl) {
  constexpr int S = 4096, D = 1024, H = 256;
  const int ti = (int)blockIdx.x;
  if (ti >= ntl[0]) return;

  __shared__ __align__(16) unsigned short lA[64 * 64];    // 8KB  (x tile, bf16, swizzled)
  __shared__ __align__(16) unsigned short lB[256 * 64];   // 32KB (W1 K-slab / W2 chunk slab)
  __shared__ __align__(16) unsigned short hS[64 * 256];   // 32KB (hidden, swizzled)

  const int t = (int)threadIdx.x;
  const int lane = t & 63;
  const int w = t >> 6;
  const int wm = w >> 2;   // 0..1
  const int wn = w & 3;    // 0..3

  const int e = tileE[ti];
  const int rowBase = tileR[ti];
  int Me = 4 * offs[e + 1] - rowBase;
  if (Me > 64) Me = 64;

  // --- phase A staging setup ---
  // x gather: thread t loads row (t>>3), elements (t&7)*8 .. +8 of each K-step (f32),
  // casts, writes one b128 to lA[row][koff^sw].
  const int ar = t >> 3;                       // 0..63
  const int arr = (ar < Me) ? ar : (Me - 1);
  const int ga = rowBase + arr;
  const float* xsrc = x + ((long)(ga & 3) * S + order[ga >> 2]) * D + (t & 7) * 8;
  unsigned short* aDst = lA + ar * 64 + (((((t & 7) * 16)) ^ ((ar & 7) << 4)) >> 1);

  // W1 staging: 4 issues x (64 rows x 16B), pre-swizzled global column.
  const unsigned short* b1src[4];
#pragma unroll
  for (int i = 0; i < 4; i++) {
    const int row = i * 64 + (t >> 3);
    b1src[i] = w1t + (long)e * H * D + (long)row * D + ((((t & 7) * 16) ^ ((row & 7) << 4)) >> 1);
  }
  const int dstE = (t >> 3) * 64 + (t & 7) * 8;

  f32x4 acc[2][4] = {};
  float4 xv0 = *(const float4*)(xsrc);
  float4 xv1 = *(const float4*)(xsrc + 4);

  for (int kt = 0; kt < 16; kt++) {
    __syncthreads();                           // prev reads of lA/lB done
    short8 av;
    av[0] = (short)f2bf(xv0.x); av[1] = (short)f2bf(xv0.y);
    av[2] = (short)f2bf(xv0.z); av[3] = (short)f2bf(xv0.w);
    av[4] = (short)f2bf(xv1.x); av[5] = (short)f2bf(xv1.y);
    av[6] = (short)f2bf(xv1.z); av[7] = (short)f2bf(xv1.w);
    *(short8*)aDst = av;
#pragma unroll
    for (int i = 0; i < 4; i++) gload16(b1src[i] + (kt << 6), lB + i * 4096 + dstE);
    if (kt < 15) {
      xv0 = *(const float4*)(xsrc + (kt + 1) * 64);
      xv1 = *(const float4*)(xsrc + (kt + 1) * 64 + 4);
    }
    __syncthreads();                           // drains vm (W1 staged) + lgkm (lA written)
#pragma unroll
    for (int kk = 0; kk < 2; kk++) {
      short8 aF[2], bF[4];
      const int kb = kk * 64 + ((lane >> 4) << 4);
#pragma unroll
      for (int mi = 0; mi < 2; mi++) {
        const int row = wm * 32 + mi * 16 + (lane & 15);
        aF[mi] = *(const short8*)((const char*)lA + row * 128 + (kb ^ ((row & 7) << 4)));
      }
#pragma unroll
      for (int ni = 0; ni < 4; ni++) {
        const int row = wn * 64 + ni * 16 + (lane & 15);
        bF[ni] = *(const short8*)((const char*)lB + row * 128 + (kb ^ ((row & 7) << 4)));
      }
#pragma unroll
      for (int mi = 0; mi < 2; mi++)
#pragma unroll
        for (int ni = 0; ni < 4; ni++)
          acc[mi][ni] = __builtin_amdgcn_mfma_f32_16x16x32_bf16(aF[mi], bF[ni], acc[mi][ni], 0, 0, 0);
    }
  }

  // bias + gelu -> hS (swizzled: byte ^= (row&7)<<4 within 512B row)
  {
    float bc[4];
#pragma unroll
    for (int ni = 0; ni < 4; ni++)
      bc[ni] = b1[e * H + wn * 64 + ni * 16 + (lane & 15)];
#pragma unroll
    for (int mi = 0; mi < 2; mi++)
#pragma unroll
      for (int j = 0; j < 4; j++) {
        const int crow = wm * 32 + mi * 16 + ((lane >> 4) << 2) + j;
#pragma unroll
        for (int ni = 0; ni < 4; ni++) {
          const int ccol = wn * 64 + ni * 16 + (lane & 15);
          const float v = gelu_exact(acc[mi][ni][j] + bc[ni]);
          hS[crow * 256 + (((ccol * 2) ^ ((crow & 7) << 4)) >> 1)] = f2bf(v);
        }
      }
  }
  __syncthreads();                             // h visible to all waves

  // --- phase B: rout = h @ W2[e] + b2[e], K=256, N in 8 chunks of 128 ---
  const unsigned short* b2base = w2t + (long)e * D * H;   // [1024][256]
  for (int nc = 0; nc < 8; nc++) {
    f32x4 a2[2][2] = {};
    for (int ks = 0; ks < 4; ks++) {
      __syncthreads();                         // prev lB reads done
#pragma unroll
      for (int i = 0; i < 2; i++) {
        const int row = i * 64 + (t >> 3);
        const unsigned short* src = b2base + (long)(nc * 128 + row) * H + (ks << 6) +
                                    ((((t & 7) * 16) ^ ((row & 7) << 4)) >> 1);
        gload16(src, lB + i * 4096 + dstE);
      }
      __syncthreads();                         // lB ready
#pragma unroll
      for (int kk = 0; kk < 2; kk++) {
        short8 aF[2], bF[2];
        const int kbh = ks * 128 + kk * 64 + ((lane >> 4) << 4);   // byte in 512B h-row
        const int kb = kk * 64 + ((lane >> 4) << 4);
#pragma unroll
        for (int mi = 0; mi < 2; mi++) {
          const int row = wm * 32 + mi * 16 + (lane & 15);
          aF[mi] = *(const short8*)((const char*)hS + row * 512 + (kbh ^ ((row & 7) << 4)));
        }
#pragma unroll
        for (int ni = 0; ni < 2; ni++) {
          const int row = wn * 32 + ni * 16 + (lane & 15);
          bF[ni] = *(const short8*)((const char*)lB + row * 128 + (kb ^ ((row & 7) << 4)));
        }
#pragma unroll
        for (int mi = 0; mi < 2; mi++)
#pragma unroll
          for (int ni = 0; ni < 2; ni++)
            a2[mi][ni] = __builtin_amdgcn_mfma_f32_16x16x32_bf16(aF[mi], bF[ni], a2[mi][ni], 0, 0, 0);
      }
    }
    // chunk epilogue: bias + scatter
    float bc2[2];
#pragma unroll
    for (int ni = 0; ni < 2; ni++)
      bc2[ni] = b2[e * D + nc * 128 + wn * 32 + ni * 16 + (lane & 15)];
#pragma unroll
    for (int mi = 0; mi < 2; mi++)
#pragma unroll
      for (int j = 0; j < 4; j++) {
        const int lrow = wm * 32 + mi * 16 + ((lane >> 4) << 2) + j;
        if (lrow >= Me) continue;
        const int g = rowBase + lrow;
        const long crow = (long)(g & 3) * S + order[g >> 2];
#pragma unroll
        for (int ni = 0; ni < 2; ni++) {
          const float v = a2[mi][ni][j] + bc2[ni];
          rout[crow * D + nc * 128 + wn * 32 + ni * 16 + (lane & 15)] = f2bf(v);
        }
      }
  }
}

// ---------------- dense 256x256x64 GEMM, 2-phase T3-minimum recipe ----------------
// Per K-tile: STAGE(next tile -> other buffer), ds_read cur, MFMA, __syncthreads().
// One barrier + one full drain per K-tile, issued AFTER compute (latency covered).
template <bool GELU, bool OUT_F32>
__global__ __launch_bounds__(512, 1) void gemm_2ph(
    const unsigned short* __restrict__ A, const unsigned short* __restrict__ BT,
    const float* __restrict__ bias, void* __restrict__ Cout,
    int N, int K, int ntiles) {
  __shared__ __align__(16) unsigned short lds[2][2][256 * 64];  // [buf][A/B] 128KB

  const int t = (int)threadIdx.x;
  const int lane = t & 63;
  const int w = t >> 6;
  const int wm = w >> 2;   // 0..1
  const int wn = w & 3;    // 0..3

  const int cpx = (int)gridDim.x >> 3;
  const int swz = ((int)blockIdx.x & 7) * cpx + ((int)blockIdx.x >> 3);
  const int mtile = swz / ntiles, ntile = swz % ntiles;

  const int tq = t & 7;
  const unsigned short* srcA[4];
  const unsigned short* srcB[4];
#pragma unroll
  for (int i = 0; i < 4; i++) {
    const int row = i * 64 + (t >> 3);
    const int koffE = ((tq * 16) ^ ((row & 7) << 4)) >> 1;
    srcA[i] = A + (long)(mtile * 256 + row) * K + koffE;
    srcB[i] = BT + (long)(ntile * 256 + row) * K + koffE;
  }
  const int dstE = (t >> 3) * 64 + tq * 8;

  auto STAGE = [&](int buf, int kt) {
    const long ko = (long)kt << 6;
#pragma unroll
    for (int i = 0; i < 4; i++) gload16(srcA[i] + ko, &lds[buf][0][i * 4096 + dstE]);
#pragma unroll
    for (int i = 0; i < 4; i++) gload16(srcB[i] + ko, &lds[buf][1][i * 4096 + dstE]);
  };

  f32x4 acc[8][4] = {};
  const int KT = K >> 6;

  STAGE(0, 0);
  __syncthreads();

  int buf = 0;
  for (int kt = 0; kt < KT; kt++) {
    if (kt + 1 < KT) STAGE(buf ^ 1, kt + 1);
#pragma unroll
    for (int kk = 0; kk < 2; kk++) {
      short8 aF[8], bF[4];
      const int kb = kk * 64 + ((lane >> 4) << 4);
#pragma unroll
      for (int m = 0; m < 8; m++) {
        const int row = wm * 128 + m * 16 + (lane & 15);
        aF[m] = *(const short8*)((const char*)&lds[buf][0][0] + row * 128 + (kb ^ ((row & 7) << 4)));
      }
#pragma unroll
      for (int n = 0; n < 4; n++) {
        const int row = wn * 64 + n * 16 + (lane & 15);
        bF[n] = *(const short8*)((const char*)&lds[buf][1][0] + row * 128 + (kb ^ ((row & 7) << 4)));
      }
      __builtin_amdgcn_s_setprio(1);
#pragma unroll
      for (int m = 0; m < 8; m++)
#pragma unroll
        for (int n = 0; n < 4; n++)
          acc[m][n] = __builtin_amdgcn_mfma_f32_16x16x32_bf16(aF[m], bF[n], acc[m][n], 0, 0, 0);
      __builtin_amdgcn_s_setprio(0);
    }
    __syncthreads();                 // vmcnt(0)+lgkmcnt(0)+barrier: next tile ready
    buf ^= 1;
  }

  float bcol[4];
#pragma unroll
  for (int n = 0; n < 4; n++)
    bcol[n] = bias[ntile * 256 + wn * 64 + n * 16 + (lane & 15)];
  const int cbase = ntile * 256 + wn * 64 + (lane & 15);
#pragma unroll
  for (int m = 0; m < 8; m++) {
#pragma unroll
    for (int j = 0; j < 4; j++) {
      const long crow = mtile * 256 + wm * 128 + m * 16 + ((lane >> 4) << 2) + j;
#pragma unroll
      for (int n = 0; n < 4; n++) {
        float v = acc[m][n][j] + bcol[n];
        if (GELU) v = gelu_exact(v);
        const long cidx = crow * (long)N + cbase + n * 16;
        if (OUT_F32) ((float*)Cout)[cidx] = v;
        else ((unsigned short*)Cout)[cidx] = f2bf(v);
      }
    }
  }
}

// ---------------- dense 256x256x64 GEMM, 8-phase (round-4 control, unchanged) ----------------
template <bool GELU, bool OUT_F32>
__global__ __launch_bounds__(512, 2) void gemm_8phase(
    const unsigned short* __restrict__ A, const unsigned short* __restrict__ BT,
    const float* __restrict__ bias, void* __restrict__ Cout,
    int N, int K, int ntiles) {
  __shared__ __align__(16) unsigned short lds[8 * 8192];

  const int t = (int)threadIdx.x;
  const int lane = t & 63;
  const int w = t >> 6;
  const int wm = w >> 2;
  const int wn = w & 3;

  const int cpx = (int)gridDim.x >> 3;
  const int swz = ((int)blockIdx.x & 7) * cpx + ((int)blockIdx.x >> 3);
  const int mtile = swz / ntiles, ntile = swz % ntiles;

  const int tq = t & 7;
  const unsigned short* srcA[2][2];
  const unsigned short* srcB[2][2];
#pragma unroll
  for (int i = 0; i < 2; i++) {
    const int ir = i * 64 + (t >> 3);
    const int koffE = ((tq * 16) ^ ((ir & 7) << 4)) >> 1;
#pragma unroll
    for (int h = 0; h < 2; h++) {
      const int ra = (ir & 63) + (h << 6) + ((ir >> 6) << 7);
      srcA[i][h] = A + (long)(mtile * 256 + ra) * K + koffE;
      const int cb = (ir & 31) + (h << 5) + ((ir >> 5) << 6);
      srcB[i][h] = BT + (long)(ntile * 256 + cb) * K + koffE;
    }
  }
  const int dstE = (t >> 3) * 64 + tq * 8;

  auto STAGE = [&](int d, int mat, int h, int kt) {
    unsigned short* dst = lds + ((d * 4 + mat * 2 + h) << 13) + dstE;
    const unsigned short* s0 = (mat == 0 ? srcA[0][h] : srcB[0][h]) + (kt << 6);
    const unsigned short* s1 = (mat == 0 ? srcA[1][h] : srcB[1][h]) + (kt << 6);
    gload16(s0, dst);
    gload16(s1, dst + 4096);
  };

  short8 aReg[8], bReg[8];
  const int klane = (lane >> 4) << 4;
  const int rsw = (lane & 7) << 4;

  auto LDA = [&](int d, int mh) {
    const char* base = (const char*)(lds + ((d * 4 + mh) << 13));
    const int r0 = wm * 64 + (lane & 15);
#pragma unroll
    for (int m = 0; m < 4; m++) {
      const int row = r0 + m * 16;
#pragma unroll
      for (int kk = 0; kk < 2; kk++)
        aReg[m * 2 + kk] = *(const short8*)(base + row * 128 + ((kk * 64 + klane) ^ rsw));
    }
  };
  auto LDB = [&](int d, int nh) {
    const char* base = (const char*)(lds + ((d * 4 + 2 + nh) << 13));
    const int r0 = wn * 32 + (lane & 15);
#pragma unroll
    for (int n = 0; n < 2; n++) {
      const int row = r0 + n * 16;
#pragma unroll
      for (int kk = 0; kk < 2; kk++)
        bReg[(nh * 2 + n) * 2 + kk] = *(const short8*)(base + row * 128 + ((kk * 64 + klane) ^ rsw));
    }
  };

  f32x4 acc[8][4] = {};
  auto MMA = [&](int mb, int nb) {
    __builtin_amdgcn_s_setprio(1);
#pragma unroll
    for (int kk = 0; kk < 2; kk++)
#pragma unroll
      for (int m = 0; m < 4; m++)
#pragma unroll
        for (int n = 0; n < 2; n++)
          acc[mb + m][nb + n] = __builtin_amdgcn_mfma_f32_16x16x32_bf16(
              aReg[m * 2 + kk], bReg[(nb + n) * 2 + kk], acc[mb + m][nb + n], 0, 0, 0);
    __builtin_amdgcn_s_setprio(0);
  };

  const int KT = K >> 6;

  {
    const int t1 = (KT > 1) ? 1 : 0;
    STAGE(0, 0, 0, 0); STAGE(0, 1, 0, 0); STAGE(0, 1, 1, 0); STAGE(0, 0, 1, 0);
    STAGE(1, 0, 0, t1); STAGE(1, 1, 0, t1); STAGE(1, 1, 1, t1);
    VMW(6);
    BARRIER();
  }

  for (int it = 0; it < (KT >> 1); ++it) {
    const int tb = (2 * it + 1 < KT) ? 2 * it + 1 : KT - 1;
    int nx = 2 * it + 2; if (nx >= KT) nx = KT - 1;
    int ny = 2 * it + 3; if (ny >= KT) ny = KT - 1;
    LDA(0, 0); LDB(0, 0); STAGE(1, 0, 1, tb);
    BARRIER();
    MMA(0, 0);
    BARRIER();
    LDB(0, 1); STAGE(0, 0, 0, nx);
    BARRIER();
    MMA(0, 2);
    BARRIER();
    LDA(0, 1); STAGE(0, 1, 0, nx);
    BARRIER();
    MMA(4, 0);
    BARRIER();
    STAGE(0, 1, 1, nx);
    BARRIER();
    MMA(4, 2);
    VMW(6);
    BARRIER();
    LDA(1, 0); LDB(1, 0); STAGE(0, 0, 1, nx);
    BARRIER();
    MMA(0, 0);
    BARRIER();
    LDB(1, 1); STAGE(1, 0, 0, ny);
    BARRIER();
    MMA(0, 2);
    BARRIER();
    LDA(1, 1); STAGE(1, 1, 0, ny);
    BARRIER();
    MMA(4, 0);
    BARRIER();
    STAGE(1, 1, 1, ny);
    BARRIER();
    MMA(4, 2);
    VMW(6);
    BARRIER();
  }
  VMW(0);

  float bcol[4];
#pragma unroll
  for (int n = 0; n < 4; n++)
    bcol[n] = bias[ntile * 256 + wn * 64 + n * 16 + (lane & 15)];
  const int cbase = ntile * 256 + wn * 64 + (lane & 15);
#pragma unroll
  for (int m = 0; m < 8; m++) {
#pragma unroll
    for (int j = 0; j < 4; j++) {
      const long crow = mtile * 256 + wm * 128 + m * 16 + ((lane >> 4) << 2) + j;
#pragma unroll
      for (int n = 0; n < 4; n++) {
        float v = acc[m][n][j] + bcol[n];
        if (GELU) v = gelu_exact(v);
        const long cidx = crow * (long)N + cbase + n * 16;
        if (OUT_F32) ((float*)Cout)[cidx] = v;
        else ((unsigned short*)Cout)[cidx] = f2bf(v);
      }
    }
  }
}

extern "C" void kernel_launch(void* const* d_in, const int* in_sizes, int n_in,
                              void* d_out, int out_size, void* d_ws, size_t ws_size,
                              hipStream_t stream) {
  const float* x   = (const float*)d_in[0];
  const int*   sid = (const int*)d_in[1];
  const float* W1  = (const float*)d_in[2];
  const float* b1  = (const float*)d_in[3];
  const float* W2  = (const float*)d_in[4];
  const float* b2  = (const float*)d_in[5];
  const float* Wg1 = (const float*)d_in[6];
  const float* bg1 = (const float*)d_in[7];
  const float* Wg2 = (const float*)d_in[8];
  const float* bg2 = (const float*)d_in[9];
  (void)in_sizes; (void)n_in; (void)out_size; (void)ws_size;

  constexpr int D = 1024, S = 4096, B = 4;
  constexpr long NT = (long)B * S;

  char* ws = (char*)d_ws;
  unsigned short* g    = (unsigned short*)(ws);
  unsigned short* w1t  = (unsigned short*)(ws + 33554432);
  unsigned short* w2t  = (unsigned short*)(ws + 41943040);
  unsigned short* wg1t = (unsigned short*)(ws + 50331648);
  unsigned short* wg2t = (unsigned short*)(ws + 52428800);
  unsigned short* rout = (unsigned short*)(ws + 62914560);
  int* offs  = (int*)(ws + 96468992);
  int* order = (int*)(ws + 96469248);
  int* tileE = (int*)(ws + 96485632);
  int* tileR = (int*)(ws + 96486912);
  int* ntl   = (int*)(ws + 96488192);

  prep_kernel<<<dim3(2560), 256, 0, stream>>>(W1, w1t, W2, w2t, Wg1, wg1t, Wg2, wg2t);
  route_kernel<<<1, 256, 0, stream>>>(sid, S, offs, order, tileE, tileR, ntl);

  // fused experts: gather+cast x -> GEMM1 -> h(LDS) -> GEMM2 -> scatter to rout
  fused_expert<<<dim3(272), 512, 0, stream>>>(
      x, w1t, b1, w2t, b2, rout, order, offs, tileE, tileR, ntl);

  // GEMM3: g = gelu(rout @ Wg1 + bg1)   [2-phase recipe — A/B test arm]
  gemm_2ph<true, false><<<dim3((unsigned)(NT / 256) * (D / 256)), 512, 0, stream>>>(
      rout, wg1t, bg1, g, D, D, D / 256);
  // GEMM4: out = g @ Wg2 + bg2          [8-phase — control arm]
  gemm_8phase<false, true><<<dim3((unsigned)(NT / 256) * (D / 256)), 512, 0, stream>>>(
      g, wg2t, bg2, d_out, D, D, D / 256);
}